// Round 9
// baseline (112.055 us; speedup 1.0000x reference)
//
#include <hip/hip_runtime.h>

#define NB 32
#define NCAND 4

#define EPS_F32   5.9604644775390625e-8f
#define UNFL_F32  1.1754943508222875e-38f
#define TOL_BD    (10.0f * EPS_F32)

__device__ __forceinline__ float fdiv(float a, float b) { return a * __builtin_amdgcn_rcpf(b); }
__device__ __forceinline__ float frcp(float a) { return __builtin_amdgcn_rcpf(a); }
__device__ __forceinline__ float fsqrt(float a) { return __builtin_amdgcn_sqrtf(a); }
__device__ __forceinline__ float frsq(float a) { return __builtin_amdgcn_rsqf(a); }

// Slim lartg: single rsqrt transcendental, single branch.
__device__ __forceinline__ void lartg(float f, float g, float* c, float* s, float* r) {
    if (g == 0.0f) { *c = 1.0f; *s = 0.0f; *r = f; }
    else {
        float ss = f * f + g * g;
        float inv_d = frsq(ss);
        float d = ss * inv_d;
        *c = fabsf(f) * inv_d;
        *r = copysignf(d, f);
        *s = g * copysignf(inv_d, f);
    }
}

__device__ __forceinline__ void las2(float f, float g, float h, float* ssmin, float* ssmax) {
    float fa = fabsf(f), ga = fabsf(g), ha = fabsf(h);
    float fhmn = fminf(fa, ha), fhmx = fmaxf(fa, ha);
    if (fhmn == 0.0f) {
        *ssmin = 0.0f;
        if (fhmx == 0.0f) *ssmax = ga;
        else {
            float mx = fmaxf(fhmx, ga), mn = fminf(fhmx, ga);
            float q = fdiv(mn, mx);
            *ssmax = mx * fsqrt(1.0f + q * q);
        }
    } else {
        if (ga < fhmx) {
            float inv_fhmx = frcp(fhmx);
            float as_ = 1.0f + fhmn * inv_fhmx;
            float at_ = (fhmx - fhmn) * inv_fhmx;
            float au = ga * inv_fhmx; au = au * au;
            float c = fdiv(2.0f, fsqrt(as_ * as_ + au) + fsqrt(at_ * at_ + au));
            *ssmin = fhmn * c;
            *ssmax = fdiv(fhmx, c);
        } else {
            float au = fdiv(fhmx, ga);
            if (au == 0.0f) { *ssmin = fdiv(fhmn * fhmx, ga); *ssmax = ga; }
            else {
                float inv_fhmx = frcp(fhmx);
                float as_ = 1.0f + fhmn * inv_fhmx;
                float at_ = (fhmx - fhmn) * inv_fhmx;
                float t1 = as_ * au, t2 = at_ * au;
                float c = frcp(fsqrt(1.0f + t1 * t1) + fsqrt(1.0f + t2 * t2));
                float sm = (fhmn * c) * au; sm = sm + sm;
                *ssmin = sm;
                *ssmax = fdiv(ga, c + c);
            }
        }
    }
}

__device__ __forceinline__ void lasv2(float f, float g, float h,
                                      float* ssmin, float* ssmax,
                                      float* snr, float* csr, float* snl, float* csl) {
    float ft = f, fa = fabsf(f), ht = h, ha = fabsf(h);
    int pmax = 1;
    bool swap_ = (ha > fa);
    if (swap_) { pmax = 3; float tt; tt = ft; ft = ht; ht = tt; tt = fa; fa = ha; ha = tt; }
    float gt = g, ga = fabsf(g);
    float clt = 0, crt = 0, slt = 0, srt = 0;
    if (ga == 0.0f) { *ssmin = ha; *ssmax = fa; clt = 1; crt = 1; slt = 0; srt = 0; }
    else {
        bool gasmal = true;
        if (ga > fa) {
            pmax = 2;
            if (fdiv(fa, ga) < EPS_F32) {
                gasmal = false;
                *ssmax = ga;
                if (ha > 1.0f) *ssmin = fdiv(fa, fdiv(ga, ha));
                else           *ssmin = fdiv(fa, ga) * ha;
                float inv_gt = frcp(gt);
                clt = 1.0f; slt = ht * inv_gt; srt = 1.0f; crt = ft * inv_gt;
            }
        }
        if (gasmal) {
            float d = fa - ha;
            float l = (d == fa) ? 1.0f : fdiv(d, fa);
            float m_ = fdiv(gt, ft);
            float t = 2.0f - l;
            float mm = m_ * m_, tt = t * t;
            float s = fsqrt(tt + mm);
            float r = (l == 0.0f) ? fabsf(m_) : fsqrt(l * l + mm);
            float a = 0.5f * (s + r);
            float inv_a = frcp(a);
            *ssmin = ha * inv_a;
            *ssmax = fa * a;
            if (mm == 0.0f) {
                if (l == 0.0f) t = copysignf(2.0f, ft) * copysignf(1.0f, gt);
                else           t = fdiv(gt, copysignf(d, ft)) + fdiv(m_, t);
            } else {
                t = (fdiv(m_, s + t) + fdiv(m_, r + l)) * (1.0f + a);
            }
            l = fsqrt(t * t + 4.0f);
            float inv_l = frcp(l);
            crt = 2.0f * inv_l; srt = t * inv_l;
            clt = (crt + srt * m_) * inv_a;
            slt = fdiv(ht, ft) * srt * inv_a;
        }
    }
    if (swap_) { *csl = srt; *snl = crt; *csr = slt; *snr = clt; }
    else       { *csl = clt; *snl = slt; *csr = crt; *snr = srt; }
    float tsign = 0.0f;
    if (pmax == 1) tsign = copysignf(1.0f, *csr) * copysignf(1.0f, *csl) * copysignf(1.0f, f);
    if (pmax == 2) tsign = copysignf(1.0f, *snr) * copysignf(1.0f, *csl) * copysignf(1.0f, g);
    if (pmax == 3) tsign = copysignf(1.0f, *snr) * copysignf(1.0f, *snl) * copysignf(1.0f, h);
    *ssmax = copysignf(*ssmax, tsign);
    *ssmin = copysignf(*ssmin, tsign * copysignf(1.0f, f) * copysignf(1.0f, h));
}

// Register-resident runtime-index access (cndmask chains; fold to direct regs
// when k is a compile-time literal).
#define D_(k) ((k)==1?dd1:(k)==2?dd2:(k)==3?dd3:dd4)
#define E_(k) ((k)==1?ee1:(k)==2?ee2:ee3)
#define Y_(k) ((k)==1?yy1:(k)==2?yy2:(k)==3?yy3:yy4)
#define SETD(k,v) do{float _v=(v);int _k=(k); if(_k==1)dd1=_v; else if(_k==2)dd2=_v; else if(_k==3)dd3=_v; else if(_k==4)dd4=_v;}while(0)
#define SETE(k,v) do{float _v=(v);int _k=(k); if(_k==1)ee1=_v; else if(_k==2)ee2=_v; else if(_k==3)ee3=_v;}while(0)
#define SETY(k,v) do{float _v=(v);int _k=(k); if(_k==1)yy1=_v; else if(_k==2)yy2=_v; else if(_k==3)yy3=_v; else if(_k==4)yy4=_v;}while(0)

// One bdsqr QR step (deflation scan + shift + chase). FAST instantiation folds
// (ll,mm)=(1,4) to literals -> all runtime-index cndmask chains and loop
// predicates constant-fold. Arithmetic is verbatim-identical to the general
// path (mechanical substitution only). Returns true if the step deflated /
// converged an edge (caller re-scans).
template<bool FAST>
__device__ __forceinline__ bool qr_step(
    int ll_in, int mm_in,
    int& idir, int& oldll, int& oldm, float& sminl,
    float smax, float thresh,
    float& dd1, float& dd2, float& dd3, float& dd4,
    float& ee1, float& ee2, float& ee3,
    float& yy1, float& yy2, float& yy3, float& yy4)
{
    const int ll = FAST ? 1 : ll_in;
    const int mm = FAST ? 4 : mm_in;

    if (ll > oldm || mm < oldll)
        idir = (fabsf(D_(ll)) >= fabsf(D_(mm))) ? 1 : 2;

    bool defl = false, cont = false;
    if (idir == 1) {
        if (fabsf(E_(mm-1)) <= TOL_BD * fabsf(D_(mm))) { SETE(mm-1, 0.0f); cont = true; }
        else {
            float mu = fabsf(D_(ll)); sminl = mu; bool dn = false;
            #pragma unroll
            for (int l = 1; l <= 3; ++l) {
                if (l >= ll && l <= mm - 1 && !dn) {
                    if (fabsf(E_(l)) <= TOL_BD * mu) { SETE(l, 0.0f); defl = true; dn = true; }
                    else {
                        mu = fabsf(D_(l+1)) * fdiv(mu, mu + fabsf(E_(l)));
                        sminl = fminf(sminl, mu);
                    }
                }
            }
        }
    } else {
        if (fabsf(E_(ll)) <= TOL_BD * fabsf(D_(ll))) { SETE(ll, 0.0f); cont = true; }
        else {
            float mu = fabsf(D_(mm)); sminl = mu; bool dn = false;
            #pragma unroll
            for (int l = 3; l >= 1; --l) {
                if (l <= mm - 1 && l >= ll && !dn) {
                    if (fabsf(E_(l)) <= TOL_BD * mu) { SETE(l, 0.0f); defl = true; dn = true; }
                    else {
                        mu = fabsf(D_(l)) * fdiv(mu, mu + fabsf(E_(l)));
                        sminl = fminf(sminl, mu);
                    }
                }
            }
        }
    }
    if (defl || cont) return true;

    oldll = ll; oldm = mm;

    float shift = 0.0f, rr;
    if (!(4.0f * TOL_BD * fdiv(sminl, smax) <= fmaxf(EPS_F32, 0.01f * TOL_BD))) {
        float sll;
        if (idir == 1) { sll = fabsf(D_(ll)); las2(D_(mm-1), E_(mm-1), D_(mm), &shift, &rr); }
        else           { sll = fabsf(D_(mm)); las2(D_(ll), E_(ll), D_(ll+1), &shift, &rr); }
        if (sll > 0.0f) { float q = fdiv(shift, sll); if (q * q < EPS_F32) shift = 0.0f; }
    }

    if (shift == 0.0f) {
        if (idir == 1) {
            float cs = 1.0f, oldcs = 1.0f, sn = 0.0f, oldsn = 0.0f, r_, nd;
            #pragma unroll
            for (int i = 1; i <= 3; ++i) {
                if (i >= ll && i <= mm - 1) {
                    lartg(D_(i) * cs, E_(i), &cs, &sn, &r_);
                    if (i > ll) SETE(i-1, oldsn * r_);
                    lartg(oldcs * r_, D_(i+1) * sn, &oldcs, &oldsn, &nd);
                    SETD(i, nd);
                    float tv = Y_(i+1), yi = Y_(i);
                    SETY(i+1, cs * tv - sn * yi);
                    SETY(i,   sn * tv + cs * yi);
                }
            }
            float h = D_(mm) * cs;
            SETD(mm, h * oldcs);
            SETE(mm-1, h * oldsn);
            if (fabsf(E_(mm-1)) <= thresh) SETE(mm-1, 0.0f);
        } else {
            float cs = 1.0f, oldcs = 1.0f, sn = 0.0f, oldsn = 0.0f, r_, nd;
            #pragma unroll
            for (int i = 4; i >= 2; --i) {
                if (i <= mm && i >= ll + 1) {
                    lartg(D_(i) * cs, E_(i-1), &cs, &sn, &r_);
                    if (i < mm) SETE(i, oldsn * r_);
                    lartg(oldcs * r_, D_(i-1) * sn, &oldcs, &oldsn, &nd);
                    SETD(i, nd);
                    float tv = Y_(i), ym = Y_(i-1);
                    SETY(i,   oldcs * tv + oldsn * ym);
                    SETY(i-1, oldcs * ym - oldsn * tv);
                }
            }
            float h = D_(ll) * cs;
            SETD(ll, h * oldcs);
            SETE(ll, h * oldsn);
            if (fabsf(E_(ll)) <= thresh) SETE(ll, 0.0f);
        }
    } else {
        if (idir == 1) {
            float f = (fabsf(D_(ll)) - shift) * (copysignf(1.0f, D_(ll)) + fdiv(shift, D_(ll)));
            float g = E_(ll), cosr, sinr, cosl, sinl, r_;
            #pragma unroll
            for (int i = 1; i <= 3; ++i) {
                if (i >= ll && i <= mm - 1) {
                    lartg(f, g, &cosr, &sinr, &r_);
                    if (i > ll) SETE(i-1, r_);
                    float di = D_(i), ei = E_(i), dp = D_(i+1);
                    f  = cosr * di + sinr * ei;
                    ei = cosr * ei - sinr * di;
                    g  = sinr * dp;
                    dp = cosr * dp;
                    lartg(f, g, &cosl, &sinl, &r_);
                    SETD(i, r_);
                    f  = cosl * ei + sinl * dp;
                    dp = cosl * dp - sinl * ei;
                    SETD(i+1, dp);
                    SETE(i, ei);
                    if (i < mm - 1) {
                        float en = E_(i+1);
                        g = sinl * en;
                        SETE(i+1, cosl * en);
                    }
                    float tv = Y_(i+1), yi = Y_(i);
                    SETY(i+1, cosr * tv - sinr * yi);
                    SETY(i,   sinr * tv + cosr * yi);
                }
            }
            SETE(mm-1, f);
            if (fabsf(E_(mm-1)) <= thresh) SETE(mm-1, 0.0f);
        } else {
            float f = (fabsf(D_(mm)) - shift) * (copysignf(1.0f, D_(mm)) + fdiv(shift, D_(mm)));
            float g = E_(mm-1), cosr, sinr, cosl, sinl, r_;
            #pragma unroll
            for (int i = 4; i >= 2; --i) {
                if (i <= mm && i >= ll + 1) {
                    lartg(f, g, &cosr, &sinr, &r_);
                    if (i < mm) SETE(i, r_);
                    float di = D_(i), em = E_(i-1), dm = D_(i-1);
                    f  = cosr * di + sinr * em;
                    em = cosr * em - sinr * di;
                    g  = sinr * dm;
                    dm = cosr * dm;
                    lartg(f, g, &cosl, &sinl, &r_);
                    SETD(i, r_);
                    f  = cosl * em + sinl * dm;
                    dm = cosl * dm - sinl * em;
                    SETD(i-1, dm);
                    SETE(i-1, em);
                    if (i > ll + 1) {
                        float en = E_(i-2);
                        g = sinl * en;
                        SETE(i-2, cosl * en);
                    }
                    float tv = Y_(i), ym = Y_(i-1);
                    SETY(i,   cosl * tv + sinl * ym);
                    SETY(i-1, cosl * ym - sinl * tv);
                }
            }
            SETE(ll, f);
            if (fabsf(E_(ll)) <= thresh) SETE(ll, 0.0f);
        }
    }
    return false;
}

// sgesdd (sgebd2 + sbdsqr) path emulation, fully register-resident.
__device__ bool tri_in_front(float x1, float y1, float x2, float y2,
                             const float* __restrict__ R, const float* __restrict__ t) {
    float A[4][4] = {
        { -1.0f,         0.0f,          x1,            0.0f         },
        {  0.0f,        -1.0f,          y1,            0.0f         },
        { x2*R[6]-R[0], x2*R[7]-R[1], x2*R[8]-R[2], x2*t[2]-t[0] },
        { y2*R[6]-R[3], y2*R[7]-R[4], y2*R[8]-R[5], y2*t[2]-t[1] }
    };
    float dd1, dd2, dd3, dd4, ee1, ee2, ee3;
    float taup0 = 0.0f, taup1 = 0.0f, p1a = 0.0f, p1b = 0.0f, p2a = 0.0f;

    // ---- sgebd2 ----
    {
        float alpha = A[0][0];
        float xn2 = A[1][0]*A[1][0] + A[2][0]*A[2][0] + A[3][0]*A[3][0];
        if (xn2 != 0.0f) {
            float beta = -copysignf(fsqrt(alpha*alpha + xn2), alpha);
            float tau = fdiv(beta - alpha, beta);
            float sc = frcp(alpha - beta);
            A[1][0] *= sc; A[2][0] *= sc; A[3][0] *= sc;
            dd1 = beta;
            #pragma unroll
            for (int j = 1; j < 4; ++j) {
                float s = A[0][j] + A[1][0]*A[1][j] + A[2][0]*A[2][j] + A[3][0]*A[3][j];
                s *= tau;
                A[0][j] -= s; A[1][j] -= s*A[1][0]; A[2][j] -= s*A[2][0]; A[3][j] -= s*A[3][0];
            }
        } else dd1 = alpha;
    }
    {
        float alpha = A[0][1];
        float xn2 = A[0][2]*A[0][2] + A[0][3]*A[0][3];
        if (xn2 != 0.0f) {
            float beta = -copysignf(fsqrt(alpha*alpha + xn2), alpha);
            taup0 = fdiv(beta - alpha, beta);
            float sc = frcp(alpha - beta);
            A[0][2] *= sc; A[0][3] *= sc;
            ee1 = beta;
            p1a = A[0][2]; p1b = A[0][3];
            #pragma unroll
            for (int r = 1; r < 4; ++r) {
                float s = A[r][1] + A[r][2]*p1a + A[r][3]*p1b;
                s *= taup0;
                A[r][1] -= s; A[r][2] -= s*p1a; A[r][3] -= s*p1b;
            }
        } else { taup0 = 0.0f; ee1 = alpha; }
    }
    {
        float alpha = A[1][1];
        float xn2 = A[2][1]*A[2][1] + A[3][1]*A[3][1];
        if (xn2 != 0.0f) {
            float beta = -copysignf(fsqrt(alpha*alpha + xn2), alpha);
            float tau = fdiv(beta - alpha, beta);
            float sc = frcp(alpha - beta);
            A[2][1] *= sc; A[3][1] *= sc;
            dd2 = beta;
            #pragma unroll
            for (int j = 2; j < 4; ++j) {
                float s = A[1][j] + A[2][1]*A[2][j] + A[3][1]*A[3][j];
                s *= tau;
                A[1][j] -= s; A[2][j] -= s*A[2][1]; A[3][j] -= s*A[3][1];
            }
        } else dd2 = alpha;
    }
    {
        float alpha = A[1][2];
        float xn2 = A[1][3]*A[1][3];
        if (xn2 != 0.0f) {
            float beta = -copysignf(fsqrt(alpha*alpha + xn2), alpha);
            taup1 = fdiv(beta - alpha, beta);
            float sc = frcp(alpha - beta);
            A[1][3] *= sc;
            ee2 = beta;
            p2a = A[1][3];
            #pragma unroll
            for (int r = 2; r < 4; ++r) {
                float s = A[r][2] + A[r][3]*p2a;
                s *= taup1;
                A[r][2] -= s; A[r][3] -= s*p2a;
            }
        } else { taup1 = 0.0f; ee2 = alpha; }
    }
    {
        float alpha = A[2][2];
        float xn2 = A[3][2]*A[3][2];
        if (xn2 != 0.0f) {
            float beta = -copysignf(fsqrt(alpha*alpha + xn2), alpha);
            float tau = fdiv(beta - alpha, beta);
            float sc = frcp(alpha - beta);
            A[3][2] *= sc;
            dd3 = beta;
            float s = A[2][3] + A[3][2]*A[3][3];
            s *= tau;
            A[2][3] -= s; A[3][3] -= s*A[3][2];
        } else dd3 = alpha;
    }
    ee3 = A[2][3];
    dd4 = A[3][3];

    // ---- y = VT_B * w ----
    float yy1, yy2, yy3, yy4;
    {
        float a1 = -taup0 * p1b;
        float a2 = -taup0 * p1b * p1a;
        float a3 = 1.0f - taup0 * p1b * p1b;
        float s2 = a2 + p2a * a3;
        yy1 = 0.0f;
        yy2 = a1;
        yy3 = a2 - taup1 * s2;
        yy4 = a3 - taup1 * s2 * p2a;
    }

    // ---- sbdsqr ----
    float sminoa = fabsf(dd1);
    if (sminoa != 0.0f) {
        float mu = sminoa;
        bool dn = false;
        #pragma unroll
        for (int i = 2; i <= 4; ++i) {
            if (!dn) {
                mu = fabsf(D_(i)) * fdiv(mu, mu + fabsf(E_(i-1)));
                sminoa = fminf(sminoa, mu);
                if (sminoa == 0.0f) dn = true;
            }
        }
    }
    sminoa = sminoa * 0.5f;
    float thresh = fmaxf(TOL_BD * sminoa, 6.0f * 16.0f * UNFL_F32);
    int mm = 4, oldll = -1, oldm = -1, idir = 0;
    float sminl = 0.0f;
    int guard = 0;

    while (mm > 1 && guard++ < 300) {
        // split scan (ll = mm-1 downto 1, first |e|<=thresh from the top)
        float smax = fabsf(D_(mm));
        int llf = 0; bool split = false;
        #pragma unroll
        for (int l = 3; l >= 1; --l) {
            if (l <= mm - 1 && !split) {
                float abse = fabsf(E_(l));
                if (abse <= thresh) { split = true; llf = l; }
                else smax = fmaxf(smax, fmaxf(fabsf(D_(l)), abse));
            }
        }
        bool cont = false;
        int ll;
        if (split) {
            SETE(llf, 0.0f);
            if (llf == mm - 1) { mm -= 1; cont = true; ll = llf; }
            else ll = llf + 1;
        } else ll = 1;

        if (!cont && ll == mm - 1) {
            // 2x2 terminal block
            float sigmn, sigmx, snr, csr, snl, csl;
            lasv2(D_(mm-1), E_(mm-1), D_(mm), &sigmn, &sigmx, &snr, &csr, &snl, &csl);
            SETD(mm-1, sigmx); SETE(mm-1, 0.0f); SETD(mm, sigmn);
            float ta = Y_(mm-1), tb = Y_(mm);
            SETY(mm-1, csr * ta + snr * tb);
            SETY(mm,   csr * tb - snr * ta);
            mm -= 2; cont = true;
        }

        if (!cont) {
            // Wave-uniform fast path: early iterations are (ll,mm)=(1,4) for
            // every active lane -> static-index instantiation (no cndmask chains).
            if (__all(ll == 1 && mm == 4)) {
                qr_step<true>(ll, mm, idir, oldll, oldm, sminl, smax, thresh,
                              dd1, dd2, dd3, dd4, ee1, ee2, ee3, yy1, yy2, yy3, yy4);
            } else {
                qr_step<false>(ll, mm, idir, oldll, oldm, sminl, smax, thresh,
                               dd1, dd2, dd3, dd4, ee1, ee2, ee3, yy1, yy2, yy3, yy4);
            }
        }
    }

    // make singular values positive
    if (dd1 < 0.0f) { dd1 = -dd1; yy1 = -yy1; }
    if (dd2 < 0.0f) { dd2 = -dd2; yy2 = -yy2; }
    if (dd3 < 0.0f) { dd3 = -dd3; yy3 = -yy3; }
    if (dd4 < 0.0f) { dd4 = -dd4; yy4 = -yy4; }

    // sort descending, LAPACK bdsqr tail semantics (ties -> later index wins)
    {
        int isub = 1; float smin = dd1;
        if (dd2 <= smin) { isub = 2; smin = dd2; }
        if (dd3 <= smin) { isub = 3; smin = dd3; }
        if (dd4 <= smin) { isub = 4; smin = dd4; }
        if (isub != 4) {
            SETD(isub, dd4); dd4 = smin;
            float tv = Y_(isub); SETY(isub, yy4); yy4 = tv;
        }
    }
    {
        int isub = 1; float smin = dd1;
        if (dd2 <= smin) { isub = 2; smin = dd2; }
        if (dd3 <= smin) { isub = 3; smin = dd3; }
        if (isub != 3) {
            SETD(isub, dd3); dd3 = smin;
            float tv = Y_(isub); SETY(isub, yy3); yy3 = tv;
        }
    }
    {
        int isub = 1; float smin = dd1;
        if (dd2 <= smin) { isub = 2; smin = dd2; }
        if (isub != 2) {
            dd1 = dd2; dd2 = smin;
            float tv = yy1; yy1 = yy2; yy2 = tv;
        }
    }

    float inv_v3 = frcp(yy4);
    float px = yy1 * inv_v3, py = yy2 * inv_v3, pz = yy3 * inv_v3;
    float z2 = R[6]*px + R[7]*py + R[8]*pz + t[2];
    return (pz > 0.0f) && (z2 > 0.0f);
}

// Candidate-major mapping; wave-aggregated LDS atomics.
__global__ __launch_bounds__(256) void score_kernel(
    const float* __restrict__ R_options,
    const float* __restrict__ t_options,
    const float* __restrict__ K_batch,
    const float* __restrict__ pts1,
    const float* __restrict__ pts2,
    const int*   __restrict__ bidx,
    int* __restrict__ scores,
    int* __restrict__ counts,
    int N)
{
    __shared__ int s_sc[NB * NCAND];
    __shared__ int s_cnt[NB];
    for (int i = threadIdx.x; i < NB * NCAND; i += blockDim.x) s_sc[i] = 0;
    for (int i = threadIdx.x; i < NB; i += blockDim.x) s_cnt[i] = 0;
    __syncthreads();

    const int tid = blockIdx.x * blockDim.x + threadIdx.x;
    if (tid < 4 * N) {
        const int c = tid / N;         // candidate (block-uniform: N % 256 == 0)
        const int i = tid - c * N;     // point
        const int b = bidx[i];
        const double inv_fx = 1.0 / (double)K_batch[b * 9 + 0];
        const double inv_fy = 1.0 / (double)K_batch[b * 9 + 4];
        const double cx = K_batch[b * 9 + 2];
        const double cy = K_batch[b * 9 + 5];
        const float x1 = (float)(((double)pts1[i * 2 + 0] - cx) * inv_fx);
        const float y1 = (float)(((double)pts1[i * 2 + 1] - cy) * inv_fy);
        const float x2 = (float)(((double)pts2[i * 2 + 0] - cx) * inv_fx);
        const float y2 = (float)(((double)pts2[i * 2 + 1] - cy) * inv_fy);

        const float* Rp = R_options + (size_t)(b * 4 + c) * 9;
        const float* tp = t_options + (size_t)(b * 4 + c) * 3;
        float R[9], t[3];
        #pragma unroll
        for (int k = 0; k < 9; ++k) R[k] = Rp[k];
        #pragma unroll
        for (int k = 0; k < 3; ++k) t[k] = tp[k];

        const bool infront = tri_in_front(x1, y1, x2, y2, R, t);

        const int lane = threadIdx.x & 63;
        const bool fullwave = (__popcll(__ballot(1)) == 64);
        const int b0 = __shfl(b, 0);
        if (fullwave && __all(b == b0)) {
            unsigned long long mb = __ballot(infront);
            if (lane == 0) {
                if (mb) atomicAdd(&s_sc[b0 * NCAND + c], (int)__popcll(mb));
                if (c == 0) atomicAdd(&s_cnt[b0], 64);
            }
        } else {
            if (infront) atomicAdd(&s_sc[b * NCAND + c], 1);
            if (c == 0)  atomicAdd(&s_cnt[b], 1);
        }
    }
    __syncthreads();

    for (int j = threadIdx.x; j < NB * NCAND; j += blockDim.x)
        if (s_sc[j]) atomicAdd(&scores[j], s_sc[j]);
    for (int j = threadIdx.x; j < NB; j += blockDim.x)
        if (s_cnt[j]) atomicAdd(&counts[j], s_cnt[j]);
}

__global__ void select_kernel(const float* __restrict__ R_options,
                              const float* __restrict__ t_options,
                              const int* __restrict__ scores,
                              const int* __restrict__ counts,
                              float* __restrict__ out)
{
    int b = threadIdx.x;
    if (b >= NB) return;
    int best = 0, bs = scores[b * 4];
    #pragma unroll
    for (int c = 1; c < 4; ++c) {
        int s = scores[b * 4 + c];
        if (s > bs) { bs = s; best = c; }   // strict > : first-max (numpy argmax)
    }
    const bool has = counts[b] > 0;
    const int bc = has ? best : 0;
    #pragma unroll
    for (int k = 0; k < 9; ++k)
        out[b * 9 + k] = has ? R_options[(b * 4 + bc) * 9 + k] : 0.0f;
    #pragma unroll
    for (int k = 0; k < 3; ++k)
        out[NB * 9 + b * 3 + k] = has ? t_options[(b * 4 + bc) * 3 + k] : 0.0f;
    out[NB * 12 + b] = (float)bc;
}

extern "C" void kernel_launch(void* const* d_in, const int* in_sizes, int n_in,
                              void* d_out, int out_size, void* d_ws, size_t ws_size,
                              hipStream_t stream) {
    const float* R_options = (const float*)d_in[0];
    const float* t_options = (const float*)d_in[1];
    const float* K_batch   = (const float*)d_in[2];
    const float* pts1      = (const float*)d_in[3];
    const float* pts2      = (const float*)d_in[4];
    const int*   bidx      = (const int*)d_in[5];
    const int N = in_sizes[5];

    int* scores = (int*)d_ws;
    int* counts = scores + NB * NCAND;

    hipMemsetAsync(d_ws, 0, (NB * NCAND + NB) * sizeof(int), stream);

    const int block = 256;
    const long long total = (long long)N * NCAND;
    const int grid = (int)((total + block - 1) / block);
    score_kernel<<<grid, block, 0, stream>>>(R_options, t_options, K_batch,
                                             pts1, pts2, bidx, scores, counts, N);
    select_kernel<<<1, 64, 0, stream>>>(R_options, t_options, scores, counts,
                                        (float*)d_out);
}

// Round 10
// 82.035 us; speedup vs baseline: 1.3660x; 1.3660x over previous
//
#include <hip/hip_runtime.h>

#define NB 32
#define NCAND 4

#define EPS_F32   5.9604644775390625e-8f
#define UNFL_F32  1.1754943508222875e-38f
#define TOL_BD    (10.0f * EPS_F32)

__device__ __forceinline__ float fdiv(float a, float b) { return a * __builtin_amdgcn_rcpf(b); }
__device__ __forceinline__ float frcp(float a) { return __builtin_amdgcn_rcpf(a); }
__device__ __forceinline__ float fsqrt(float a) { return __builtin_amdgcn_sqrtf(a); }
__device__ __forceinline__ float frsq(float a) { return __builtin_amdgcn_rsqf(a); }

// Slim lartg: single rsqrt transcendental, single branch.
__device__ __forceinline__ void lartg(float f, float g, float* c, float* s, float* r) {
    if (g == 0.0f) { *c = 1.0f; *s = 0.0f; *r = f; }
    else {
        float ss = f * f + g * g;
        float inv_d = frsq(ss);
        float d = ss * inv_d;
        *c = fabsf(f) * inv_d;
        *r = copysignf(d, f);
        *s = g * copysignf(inv_d, f);
    }
}

__device__ __forceinline__ void las2(float f, float g, float h, float* ssmin, float* ssmax) {
    float fa = fabsf(f), ga = fabsf(g), ha = fabsf(h);
    float fhmn = fminf(fa, ha), fhmx = fmaxf(fa, ha);
    if (fhmn == 0.0f) {
        *ssmin = 0.0f;
        if (fhmx == 0.0f) *ssmax = ga;
        else {
            float mx = fmaxf(fhmx, ga), mn = fminf(fhmx, ga);
            float q = fdiv(mn, mx);
            *ssmax = mx * fsqrt(1.0f + q * q);
        }
    } else {
        if (ga < fhmx) {
            float inv_fhmx = frcp(fhmx);
            float as_ = 1.0f + fhmn * inv_fhmx;
            float at_ = (fhmx - fhmn) * inv_fhmx;
            float au = ga * inv_fhmx; au = au * au;
            float c = fdiv(2.0f, fsqrt(as_ * as_ + au) + fsqrt(at_ * at_ + au));
            *ssmin = fhmn * c;
            *ssmax = fdiv(fhmx, c);
        } else {
            float au = fdiv(fhmx, ga);
            if (au == 0.0f) { *ssmin = fdiv(fhmn * fhmx, ga); *ssmax = ga; }
            else {
                float inv_fhmx = frcp(fhmx);
                float as_ = 1.0f + fhmn * inv_fhmx;
                float at_ = (fhmx - fhmn) * inv_fhmx;
                float t1 = as_ * au, t2 = at_ * au;
                float c = frcp(fsqrt(1.0f + t1 * t1) + fsqrt(1.0f + t2 * t2));
                float sm = (fhmn * c) * au; sm = sm + sm;
                *ssmin = sm;
                *ssmax = fdiv(ga, c + c);
            }
        }
    }
}

__device__ __forceinline__ void lasv2(float f, float g, float h,
                                      float* ssmin, float* ssmax,
                                      float* snr, float* csr, float* snl, float* csl) {
    float ft = f, fa = fabsf(f), ht = h, ha = fabsf(h);
    int pmax = 1;
    bool swap_ = (ha > fa);
    if (swap_) { pmax = 3; float tt; tt = ft; ft = ht; ht = tt; tt = fa; fa = ha; ha = tt; }
    float gt = g, ga = fabsf(g);
    float clt = 0, crt = 0, slt = 0, srt = 0;
    if (ga == 0.0f) { *ssmin = ha; *ssmax = fa; clt = 1; crt = 1; slt = 0; srt = 0; }
    else {
        bool gasmal = true;
        if (ga > fa) {
            pmax = 2;
            if (fdiv(fa, ga) < EPS_F32) {
                gasmal = false;
                *ssmax = ga;
                if (ha > 1.0f) *ssmin = fdiv(fa, fdiv(ga, ha));
                else           *ssmin = fdiv(fa, ga) * ha;
                float inv_gt = frcp(gt);
                clt = 1.0f; slt = ht * inv_gt; srt = 1.0f; crt = ft * inv_gt;
            }
        }
        if (gasmal) {
            float d = fa - ha;
            float l = (d == fa) ? 1.0f : fdiv(d, fa);
            float m_ = fdiv(gt, ft);
            float t = 2.0f - l;
            float mm = m_ * m_, tt = t * t;
            float s = fsqrt(tt + mm);
            float r = (l == 0.0f) ? fabsf(m_) : fsqrt(l * l + mm);
            float a = 0.5f * (s + r);
            float inv_a = frcp(a);
            *ssmin = ha * inv_a;
            *ssmax = fa * a;
            if (mm == 0.0f) {
                if (l == 0.0f) t = copysignf(2.0f, ft) * copysignf(1.0f, gt);
                else           t = fdiv(gt, copysignf(d, ft)) + fdiv(m_, t);
            } else {
                t = (fdiv(m_, s + t) + fdiv(m_, r + l)) * (1.0f + a);
            }
            l = fsqrt(t * t + 4.0f);
            float inv_l = frcp(l);
            crt = 2.0f * inv_l; srt = t * inv_l;
            clt = (crt + srt * m_) * inv_a;
            slt = fdiv(ht, ft) * srt * inv_a;
        }
    }
    if (swap_) { *csl = srt; *snl = crt; *csr = slt; *snr = clt; }
    else       { *csl = clt; *snl = slt; *csr = crt; *snr = srt; }
    float tsign = 0.0f;
    if (pmax == 1) tsign = copysignf(1.0f, *csr) * copysignf(1.0f, *csl) * copysignf(1.0f, f);
    if (pmax == 2) tsign = copysignf(1.0f, *snr) * copysignf(1.0f, *csl) * copysignf(1.0f, g);
    if (pmax == 3) tsign = copysignf(1.0f, *snr) * copysignf(1.0f, *snl) * copysignf(1.0f, h);
    *ssmax = copysignf(*ssmax, tsign);
    *ssmin = copysignf(*ssmin, tsign * copysignf(1.0f, f) * copysignf(1.0f, h));
}

// Register-resident runtime-index access (cndmask chains; fold to direct regs
// when index is a compile-time literal).
#define D_(k) ((k)==1?dd1:(k)==2?dd2:(k)==3?dd3:dd4)
#define E_(k) ((k)==1?ee1:(k)==2?ee2:ee3)
#define Y_(k) ((k)==1?yy1:(k)==2?yy2:(k)==3?yy3:yy4)
#define SETD(k,v) do{float _v=(v);int _k=(k); if(_k==1)dd1=_v; else if(_k==2)dd2=_v; else if(_k==3)dd3=_v; else if(_k==4)dd4=_v;}while(0)
#define SETE(k,v) do{float _v=(v);int _k=(k); if(_k==1)ee1=_v; else if(_k==2)ee2=_v; else if(_k==3)ee3=_v;}while(0)
#define SETY(k,v) do{float _v=(v);int _k=(k); if(_k==1)yy1=_v; else if(_k==2)yy2=_v; else if(_k==3)yy3=_v; else if(_k==4)yy4=_v;}while(0)

// One bdsqr QR step (deflation scan + shift + chase), textual macro so the
// (1,4) instantiation constant-folds all index chains WITHOUT any function
// call / reference params (R9 lesson: float& params -> address-taken ->
// scratch spill, FETCH 1.4->8.7MB). Verbatim R8 arithmetic.
#define QR_BODY(LLc, MMc)                                                      \
{                                                                              \
    if ((LLc) > oldm || (MMc) < oldll)                                         \
        idir = (fabsf(D_(LLc)) >= fabsf(D_(MMc))) ? 1 : 2;                     \
    bool defl = false;                                                         \
    if (idir == 1) {                                                           \
        if (fabsf(E_((MMc)-1)) <= TOL_BD * fabsf(D_(MMc))) { SETE((MMc)-1, 0.0f); cont = true; } \
        else {                                                                 \
            float mu = fabsf(D_(LLc)); sminl = mu; bool dn = false;            \
            _Pragma("unroll")                                                  \
            for (int l = 1; l <= 3; ++l) {                                     \
                if (l >= (LLc) && l <= (MMc) - 1 && !dn) {                     \
                    if (fabsf(E_(l)) <= TOL_BD * mu) { SETE(l, 0.0f); defl = true; dn = true; } \
                    else {                                                     \
                        mu = fabsf(D_(l+1)) * fdiv(mu, mu + fabsf(E_(l)));     \
                        sminl = fminf(sminl, mu);                              \
                    }                                                          \
                }                                                              \
            }                                                                  \
        }                                                                      \
    } else {                                                                   \
        if (fabsf(E_(LLc)) <= TOL_BD * fabsf(D_(LLc))) { SETE(LLc, 0.0f); cont = true; } \
        else {                                                                 \
            float mu = fabsf(D_(MMc)); sminl = mu; bool dn = false;            \
            _Pragma("unroll")                                                  \
            for (int l = 3; l >= 1; --l) {                                     \
                if (l <= (MMc) - 1 && l >= (LLc) && !dn) {                     \
                    if (fabsf(E_(l)) <= TOL_BD * mu) { SETE(l, 0.0f); defl = true; dn = true; } \
                    else {                                                     \
                        mu = fabsf(D_(l)) * fdiv(mu, mu + fabsf(E_(l)));       \
                        sminl = fminf(sminl, mu);                              \
                    }                                                          \
                }                                                              \
            }                                                                  \
        }                                                                      \
    }                                                                          \
    if (defl) cont = true;                                                     \
    if (!cont) {                                                               \
        oldll = (LLc); oldm = (MMc);                                           \
        float shift = 0.0f, rr;                                                \
        if (!(4.0f * TOL_BD * fdiv(sminl, smax) <= fmaxf(EPS_F32, 0.01f * TOL_BD))) { \
            float sll;                                                         \
            if (idir == 1) { sll = fabsf(D_(LLc)); las2(D_((MMc)-1), E_((MMc)-1), D_(MMc), &shift, &rr); } \
            else           { sll = fabsf(D_(MMc)); las2(D_(LLc), E_(LLc), D_((LLc)+1), &shift, &rr); } \
            if (sll > 0.0f) { float q = fdiv(shift, sll); if (q * q < EPS_F32) shift = 0.0f; } \
        }                                                                      \
        if (shift == 0.0f) {                                                   \
            if (idir == 1) {                                                   \
                float cs = 1.0f, oldcs = 1.0f, sn = 0.0f, oldsn = 0.0f, r_, nd; \
                _Pragma("unroll")                                              \
                for (int i = 1; i <= 3; ++i) {                                 \
                    if (i >= (LLc) && i <= (MMc) - 1) {                        \
                        lartg(D_(i) * cs, E_(i), &cs, &sn, &r_);               \
                        if (i > (LLc)) SETE(i-1, oldsn * r_);                  \
                        lartg(oldcs * r_, D_(i+1) * sn, &oldcs, &oldsn, &nd);  \
                        SETD(i, nd);                                           \
                        float tv = Y_(i+1), yi = Y_(i);                        \
                        SETY(i+1, cs * tv - sn * yi);                          \
                        SETY(i,   sn * tv + cs * yi);                          \
                    }                                                          \
                }                                                              \
                float h = D_(MMc) * cs;                                        \
                SETD(MMc, h * oldcs);                                          \
                SETE((MMc)-1, h * oldsn);                                      \
                if (fabsf(E_((MMc)-1)) <= thresh) SETE((MMc)-1, 0.0f);         \
            } else {                                                           \
                float cs = 1.0f, oldcs = 1.0f, sn = 0.0f, oldsn = 0.0f, r_, nd; \
                _Pragma("unroll")                                              \
                for (int i = 4; i >= 2; --i) {                                 \
                    if (i <= (MMc) && i >= (LLc) + 1) {                        \
                        lartg(D_(i) * cs, E_(i-1), &cs, &sn, &r_);             \
                        if (i < (MMc)) SETE(i, oldsn * r_);                    \
                        lartg(oldcs * r_, D_(i-1) * sn, &oldcs, &oldsn, &nd);  \
                        SETD(i, nd);                                           \
                        float tv = Y_(i), ym = Y_(i-1);                        \
                        SETY(i,   oldcs * tv + oldsn * ym);                    \
                        SETY(i-1, oldcs * ym - oldsn * tv);                    \
                    }                                                          \
                }                                                              \
                float h = D_(LLc) * cs;                                        \
                SETD(LLc, h * oldcs);                                          \
                SETE(LLc, h * oldsn);                                          \
                if (fabsf(E_(LLc)) <= thresh) SETE(LLc, 0.0f);                 \
            }                                                                  \
        } else {                                                               \
            if (idir == 1) {                                                   \
                float f = (fabsf(D_(LLc)) - shift) * (copysignf(1.0f, D_(LLc)) + fdiv(shift, D_(LLc))); \
                float g = E_(LLc), cosr, sinr, cosl, sinl, r_;                 \
                _Pragma("unroll")                                              \
                for (int i = 1; i <= 3; ++i) {                                 \
                    if (i >= (LLc) && i <= (MMc) - 1) {                        \
                        lartg(f, g, &cosr, &sinr, &r_);                        \
                        if (i > (LLc)) SETE(i-1, r_);                          \
                        float di = D_(i), ei = E_(i), dp = D_(i+1);            \
                        f  = cosr * di + sinr * ei;                            \
                        ei = cosr * ei - sinr * di;                            \
                        g  = sinr * dp;                                        \
                        dp = cosr * dp;                                        \
                        lartg(f, g, &cosl, &sinl, &r_);                        \
                        SETD(i, r_);                                           \
                        f  = cosl * ei + sinl * dp;                            \
                        dp = cosl * dp - sinl * ei;                            \
                        SETD(i+1, dp);                                         \
                        SETE(i, ei);                                           \
                        if (i < (MMc) - 1) {                                   \
                            float en = E_(i+1);                                \
                            g = sinl * en;                                     \
                            SETE(i+1, cosl * en);                              \
                        }                                                      \
                        float tv = Y_(i+1), yi = Y_(i);                        \
                        SETY(i+1, cosr * tv - sinr * yi);                      \
                        SETY(i,   sinr * tv + cosr * yi);                      \
                    }                                                          \
                }                                                              \
                SETE((MMc)-1, f);                                              \
                if (fabsf(E_((MMc)-1)) <= thresh) SETE((MMc)-1, 0.0f);         \
            } else {                                                           \
                float f = (fabsf(D_(MMc)) - shift) * (copysignf(1.0f, D_(MMc)) + fdiv(shift, D_(MMc))); \
                float g = E_((MMc)-1), cosr, sinr, cosl, sinl, r_;             \
                _Pragma("unroll")                                              \
                for (int i = 4; i >= 2; --i) {                                 \
                    if (i <= (MMc) && i >= (LLc) + 1) {                        \
                        lartg(f, g, &cosr, &sinr, &r_);                        \
                        if (i < (MMc)) SETE(i, r_);                            \
                        float di = D_(i), em = E_(i-1), dm = D_(i-1);          \
                        f  = cosr * di + sinr * em;                            \
                        em = cosr * em - sinr * di;                            \
                        g  = sinr * dm;                                        \
                        dm = cosr * dm;                                        \
                        lartg(f, g, &cosl, &sinl, &r_);                        \
                        SETD(i, r_);                                           \
                        f  = cosl * em + sinl * dm;                            \
                        dm = cosl * dm - sinl * em;                            \
                        SETD(i-1, dm);                                         \
                        SETE(i-1, em);                                         \
                        if (i > (LLc) + 1) {                                   \
                            float en = E_(i-2);                                \
                            g = sinl * en;                                     \
                            SETE(i-2, cosl * en);                              \
                        }                                                      \
                        float tv = Y_(i), ym = Y_(i-1);                        \
                        SETY(i,   cosl * tv + sinl * ym);                      \
                        SETY(i-1, cosl * ym - sinl * tv);                      \
                    }                                                          \
                }                                                              \
                SETE(LLc, f);                                                  \
                if (fabsf(E_(LLc)) <= thresh) SETE(LLc, 0.0f);                 \
            }                                                                  \
        }                                                                      \
    }                                                                          \
}

// sgesdd (sgebd2 + sbdsqr) path emulation, fully register-resident.
__device__ bool tri_in_front(float x1, float y1, float x2, float y2,
                             const float* __restrict__ R, const float* __restrict__ t) {
    float A[4][4] = {
        { -1.0f,         0.0f,          x1,            0.0f         },
        {  0.0f,        -1.0f,          y1,            0.0f         },
        { x2*R[6]-R[0], x2*R[7]-R[1], x2*R[8]-R[2], x2*t[2]-t[0] },
        { y2*R[6]-R[3], y2*R[7]-R[4], y2*R[8]-R[5], y2*t[2]-t[1] }
    };
    float dd1, dd2, dd3, dd4, ee1, ee2, ee3;
    float taup0 = 0.0f, taup1 = 0.0f, p1a = 0.0f, p1b = 0.0f, p2a = 0.0f;

    // ---- sgebd2 ----
    {
        float alpha = A[0][0];
        float xn2 = A[1][0]*A[1][0] + A[2][0]*A[2][0] + A[3][0]*A[3][0];
        if (xn2 != 0.0f) {
            float beta = -copysignf(fsqrt(alpha*alpha + xn2), alpha);
            float tau = fdiv(beta - alpha, beta);
            float sc = frcp(alpha - beta);
            A[1][0] *= sc; A[2][0] *= sc; A[3][0] *= sc;
            dd1 = beta;
            #pragma unroll
            for (int j = 1; j < 4; ++j) {
                float s = A[0][j] + A[1][0]*A[1][j] + A[2][0]*A[2][j] + A[3][0]*A[3][j];
                s *= tau;
                A[0][j] -= s; A[1][j] -= s*A[1][0]; A[2][j] -= s*A[2][0]; A[3][j] -= s*A[3][0];
            }
        } else dd1 = alpha;
    }
    {
        float alpha = A[0][1];
        float xn2 = A[0][2]*A[0][2] + A[0][3]*A[0][3];
        if (xn2 != 0.0f) {
            float beta = -copysignf(fsqrt(alpha*alpha + xn2), alpha);
            taup0 = fdiv(beta - alpha, beta);
            float sc = frcp(alpha - beta);
            A[0][2] *= sc; A[0][3] *= sc;
            ee1 = beta;
            p1a = A[0][2]; p1b = A[0][3];
            #pragma unroll
            for (int r = 1; r < 4; ++r) {
                float s = A[r][1] + A[r][2]*p1a + A[r][3]*p1b;
                s *= taup0;
                A[r][1] -= s; A[r][2] -= s*p1a; A[r][3] -= s*p1b;
            }
        } else { taup0 = 0.0f; ee1 = alpha; }
    }
    {
        float alpha = A[1][1];
        float xn2 = A[2][1]*A[2][1] + A[3][1]*A[3][1];
        if (xn2 != 0.0f) {
            float beta = -copysignf(fsqrt(alpha*alpha + xn2), alpha);
            float tau = fdiv(beta - alpha, beta);
            float sc = frcp(alpha - beta);
            A[2][1] *= sc; A[3][1] *= sc;
            dd2 = beta;
            #pragma unroll
            for (int j = 2; j < 4; ++j) {
                float s = A[1][j] + A[2][1]*A[2][j] + A[3][1]*A[3][j];
                s *= tau;
                A[1][j] -= s; A[2][j] -= s*A[2][1]; A[3][j] -= s*A[3][1];
            }
        } else dd2 = alpha;
    }
    {
        float alpha = A[1][2];
        float xn2 = A[1][3]*A[1][3];
        if (xn2 != 0.0f) {
            float beta = -copysignf(fsqrt(alpha*alpha + xn2), alpha);
            taup1 = fdiv(beta - alpha, beta);
            float sc = frcp(alpha - beta);
            A[1][3] *= sc;
            ee2 = beta;
            p2a = A[1][3];
            #pragma unroll
            for (int r = 2; r < 4; ++r) {
                float s = A[r][2] + A[r][3]*p2a;
                s *= taup1;
                A[r][2] -= s; A[r][3] -= s*p2a;
            }
        } else { taup1 = 0.0f; ee2 = alpha; }
    }
    {
        float alpha = A[2][2];
        float xn2 = A[3][2]*A[3][2];
        if (xn2 != 0.0f) {
            float beta = -copysignf(fsqrt(alpha*alpha + xn2), alpha);
            float tau = fdiv(beta - alpha, beta);
            float sc = frcp(alpha - beta);
            A[3][2] *= sc;
            dd3 = beta;
            float s = A[2][3] + A[3][2]*A[3][3];
            s *= tau;
            A[2][3] -= s; A[3][3] -= s*A[3][2];
        } else dd3 = alpha;
    }
    ee3 = A[2][3];
    dd4 = A[3][3];

    // ---- y = VT_B * w ----
    float yy1, yy2, yy3, yy4;
    {
        float a1 = -taup0 * p1b;
        float a2 = -taup0 * p1b * p1a;
        float a3 = 1.0f - taup0 * p1b * p1b;
        float s2 = a2 + p2a * a3;
        yy1 = 0.0f;
        yy2 = a1;
        yy3 = a2 - taup1 * s2;
        yy4 = a3 - taup1 * s2 * p2a;
    }

    // ---- sbdsqr ----
    float sminoa = fabsf(dd1);
    if (sminoa != 0.0f) {
        float mu = sminoa;
        bool dn = false;
        #pragma unroll
        for (int i = 2; i <= 4; ++i) {
            if (!dn) {
                mu = fabsf(D_(i)) * fdiv(mu, mu + fabsf(E_(i-1)));
                sminoa = fminf(sminoa, mu);
                if (sminoa == 0.0f) dn = true;
            }
        }
    }
    sminoa = sminoa * 0.5f;
    float thresh = fmaxf(TOL_BD * sminoa, 6.0f * 16.0f * UNFL_F32);
    int mm = 4, oldll = -1, oldm = -1, idir = 0;
    float sminl = 0.0f;
    int guard = 0;

    while (mm > 1 && guard++ < 300) {
        // split scan (ll = mm-1 downto 1, first |e|<=thresh from the top)
        float smax = fabsf(D_(mm));
        int llf = 0; bool split = false;
        #pragma unroll
        for (int l = 3; l >= 1; --l) {
            if (l <= mm - 1 && !split) {
                float abse = fabsf(E_(l));
                if (abse <= thresh) { split = true; llf = l; }
                else smax = fmaxf(smax, fmaxf(fabsf(D_(l)), abse));
            }
        }
        bool cont = false;
        int ll;
        if (split) {
            SETE(llf, 0.0f);
            if (llf == mm - 1) { mm -= 1; cont = true; ll = llf; }
            else ll = llf + 1;
        } else ll = 1;

        if (!cont && ll == mm - 1) {
            // 2x2 terminal block
            float sigmn, sigmx, snr, csr, snl, csl;
            lasv2(D_(mm-1), E_(mm-1), D_(mm), &sigmn, &sigmx, &snr, &csr, &snl, &csl);
            SETD(mm-1, sigmx); SETE(mm-1, 0.0f); SETD(mm, sigmn);
            float ta = Y_(mm-1), tb = Y_(mm);
            SETY(mm-1, csr * ta + snr * tb);
            SETY(mm,   csr * tb - snr * ta);
            mm -= 2; cont = true;
        }

        if (!cont) {
            // Wave-uniform fast path: early iterations are (ll,mm)=(1,4) for
            // every active lane -> literal expansion, all index chains fold.
            if (__all(ll == 1 && mm == 4)) {
                QR_BODY(1, 4)
            } else {
                QR_BODY(ll, mm)
            }
        }
    }

    // make singular values positive
    if (dd1 < 0.0f) { dd1 = -dd1; yy1 = -yy1; }
    if (dd2 < 0.0f) { dd2 = -dd2; yy2 = -yy2; }
    if (dd3 < 0.0f) { dd3 = -dd3; yy3 = -yy3; }
    if (dd4 < 0.0f) { dd4 = -dd4; yy4 = -yy4; }

    // sort descending, LAPACK bdsqr tail semantics (ties -> later index wins)
    {
        int isub = 1; float smin = dd1;
        if (dd2 <= smin) { isub = 2; smin = dd2; }
        if (dd3 <= smin) { isub = 3; smin = dd3; }
        if (dd4 <= smin) { isub = 4; smin = dd4; }
        if (isub != 4) {
            SETD(isub, dd4); dd4 = smin;
            float tv = Y_(isub); SETY(isub, yy4); yy4 = tv;
        }
    }
    {
        int isub = 1; float smin = dd1;
        if (dd2 <= smin) { isub = 2; smin = dd2; }
        if (dd3 <= smin) { isub = 3; smin = dd3; }
        if (isub != 3) {
            SETD(isub, dd3); dd3 = smin;
            float tv = Y_(isub); SETY(isub, yy3); yy3 = tv;
        }
    }
    {
        int isub = 1; float smin = dd1;
        if (dd2 <= smin) { isub = 2; smin = dd2; }
        if (isub != 2) {
            dd1 = dd2; dd2 = smin;
            float tv = yy1; yy1 = yy2; yy2 = tv;
        }
    }

    float inv_v3 = frcp(yy4);
    float px = yy1 * inv_v3, py = yy2 * inv_v3, pz = yy3 * inv_v3;
    float z2 = R[6]*px + R[7]*py + R[8]*pz + t[2];
    return (pz > 0.0f) && (z2 > 0.0f);
}

// Candidate-major mapping; wave-aggregated LDS atomics.
__global__ __launch_bounds__(256) void score_kernel(
    const float* __restrict__ R_options,
    const float* __restrict__ t_options,
    const float* __restrict__ K_batch,
    const float* __restrict__ pts1,
    const float* __restrict__ pts2,
    const int*   __restrict__ bidx,
    int* __restrict__ scores,
    int* __restrict__ counts,
    int N)
{
    __shared__ int s_sc[NB * NCAND];
    __shared__ int s_cnt[NB];
    for (int i = threadIdx.x; i < NB * NCAND; i += blockDim.x) s_sc[i] = 0;
    for (int i = threadIdx.x; i < NB; i += blockDim.x) s_cnt[i] = 0;
    __syncthreads();

    const int tid = blockIdx.x * blockDim.x + threadIdx.x;
    if (tid < 4 * N) {
        const int c = tid / N;         // candidate (block-uniform: N % 256 == 0)
        const int i = tid - c * N;     // point
        const int b = bidx[i];
        const double inv_fx = 1.0 / (double)K_batch[b * 9 + 0];
        const double inv_fy = 1.0 / (double)K_batch[b * 9 + 4];
        const double cx = K_batch[b * 9 + 2];
        const double cy = K_batch[b * 9 + 5];
        const float x1 = (float)(((double)pts1[i * 2 + 0] - cx) * inv_fx);
        const float y1 = (float)(((double)pts1[i * 2 + 1] - cy) * inv_fy);
        const float x2 = (float)(((double)pts2[i * 2 + 0] - cx) * inv_fx);
        const float y2 = (float)(((double)pts2[i * 2 + 1] - cy) * inv_fy);

        const float* Rp = R_options + (size_t)(b * 4 + c) * 9;
        const float* tp = t_options + (size_t)(b * 4 + c) * 3;
        float R[9], t[3];
        #pragma unroll
        for (int k = 0; k < 9; ++k) R[k] = Rp[k];
        #pragma unroll
        for (int k = 0; k < 3; ++k) t[k] = tp[k];

        const bool infront = tri_in_front(x1, y1, x2, y2, R, t);

        const int lane = threadIdx.x & 63;
        const bool fullwave = (__popcll(__ballot(1)) == 64);
        const int b0 = __shfl(b, 0);
        if (fullwave && __all(b == b0)) {
            unsigned long long mb = __ballot(infront);
            if (lane == 0) {
                if (mb) atomicAdd(&s_sc[b0 * NCAND + c], (int)__popcll(mb));
                if (c == 0) atomicAdd(&s_cnt[b0], 64);
            }
        } else {
            if (infront) atomicAdd(&s_sc[b * NCAND + c], 1);
            if (c == 0)  atomicAdd(&s_cnt[b], 1);
        }
    }
    __syncthreads();

    for (int j = threadIdx.x; j < NB * NCAND; j += blockDim.x)
        if (s_sc[j]) atomicAdd(&scores[j], s_sc[j]);
    for (int j = threadIdx.x; j < NB; j += blockDim.x)
        if (s_cnt[j]) atomicAdd(&counts[j], s_cnt[j]);
}

__global__ void select_kernel(const float* __restrict__ R_options,
                              const float* __restrict__ t_options,
                              const int* __restrict__ scores,
                              const int* __restrict__ counts,
                              float* __restrict__ out)
{
    int b = threadIdx.x;
    if (b >= NB) return;
    int best = 0, bs = scores[b * 4];
    #pragma unroll
    for (int c = 1; c < 4; ++c) {
        int s = scores[b * 4 + c];
        if (s > bs) { bs = s; best = c; }   // strict > : first-max (numpy argmax)
    }
    const bool has = counts[b] > 0;
    const int bc = has ? best : 0;
    #pragma unroll
    for (int k = 0; k < 9; ++k)
        out[b * 9 + k] = has ? R_options[(b * 4 + bc) * 9 + k] : 0.0f;
    #pragma unroll
    for (int k = 0; k < 3; ++k)
        out[NB * 9 + b * 3 + k] = has ? t_options[(b * 4 + bc) * 3 + k] : 0.0f;
    out[NB * 12 + b] = (float)bc;
}

extern "C" void kernel_launch(void* const* d_in, const int* in_sizes, int n_in,
                              void* d_out, int out_size, void* d_ws, size_t ws_size,
                              hipStream_t stream) {
    const float* R_options = (const float*)d_in[0];
    const float* t_options = (const float*)d_in[1];
    const float* K_batch   = (const float*)d_in[2];
    const float* pts1      = (const float*)d_in[3];
    const float* pts2      = (const float*)d_in[4];
    const int*   bidx      = (const int*)d_in[5];
    const int N = in_sizes[5];

    int* scores = (int*)d_ws;
    int* counts = scores + NB * NCAND;

    hipMemsetAsync(d_ws, 0, (NB * NCAND + NB) * sizeof(int), stream);

    const int block = 256;
    const long long total = (long long)N * NCAND;
    const int grid = (int)((total + block - 1) / block);
    score_kernel<<<grid, block, 0, stream>>>(R_options, t_options, K_batch,
                                             pts1, pts2, bidx, scores, counts, N);
    select_kernel<<<1, 64, 0, stream>>>(R_options, t_options, scores, counts,
                                        (float*)d_out);
}